// Round 2
// baseline (197.137 us; speedup 1.0000x reference)
//
#include <hip/hip_runtime.h>

#define NBINS 256
#define NCOPY 16
#define HSTRIDE 257  // 257 % 32 == 1 -> copy c of bin b sits in bank (c + b) % 32

// ---- order-preserving float<->uint encoding for atomic min/max ----
__device__ __forceinline__ unsigned int f2o(float f) {
    unsigned int u = __float_as_uint(f);
    return (u & 0x80000000u) ? ~u : (u | 0x80000000u);
}
__device__ __forceinline__ float o2f(unsigned int u) {
    unsigned int v = (u & 0x80000000u) ? (u & 0x7fffffffu) : ~u;
    return __uint_as_float(v);
}

// ws layout (uint32): ws[0]=ordered min, ws[1]=ordered max, ws[2..257]=hist bins
__global__ void hrt_init(unsigned int* ws) {
    int i = threadIdx.x;
    if (i == 0) ws[0] = 0xFFFFFFFFu;
    if (i == 1) ws[1] = 0u;
    ws[2 + i] = 0u;  // blockDim.x == NBINS
}

__global__ void hrt_minmax(const float4* __restrict__ in, int n4, unsigned int* ws) {
    float mn = INFINITY, mx = -INFINITY;
    int stride = gridDim.x * blockDim.x;
    for (int i = blockIdx.x * blockDim.x + threadIdx.x; i < n4; i += stride) {
        float4 v = in[i];
        mn = fminf(mn, fminf(fminf(v.x, v.y), fminf(v.z, v.w)));
        mx = fmaxf(mx, fmaxf(fmaxf(v.x, v.y), fmaxf(v.z, v.w)));
    }
    #pragma unroll
    for (int off = 32; off > 0; off >>= 1) {
        mn = fminf(mn, __shfl_down(mn, off));
        mx = fmaxf(mx, __shfl_down(mx, off));
    }
    __shared__ float smn[4], smx[4];
    int lane = threadIdx.x & 63, wid = threadIdx.x >> 6;
    if (lane == 0) { smn[wid] = mn; smx[wid] = mx; }
    __syncthreads();
    if (threadIdx.x == 0) {
        #pragma unroll
        for (int w = 1; w < 4; ++w) { mn = fminf(mn, smn[w]); mx = fmaxf(mx, smx[w]); }
        atomicMin(&ws[0], f2o(mn));
        atomicMax(&ws[1], f2o(mx));
    }
}

__global__ void hrt_hist(const float4* __restrict__ in, int n4,
                         const unsigned int* __restrict__ ws) {
    __shared__ unsigned int h[NCOPY * HSTRIDE];
    for (int i = threadIdx.x; i < NCOPY * HSTRIDE; i += blockDim.x)
        h[i] = 0u;
    __syncthreads();
    float mn = o2f(ws[0]);
    float mx = o2f(ws[1]);
    float scale = (float)NBINS / (mx - mn);
    unsigned int base = (threadIdx.x & (NCOPY - 1)) * HSTRIDE;
    int stride = gridDim.x * blockDim.x;
    for (int i = blockIdx.x * blockDim.x + threadIdx.x; i < n4; i += stride) {
        float4 v = in[i];
        int b0 = (int)((v.x - mn) * scale); b0 = b0 > NBINS - 1 ? NBINS - 1 : b0;
        int b1 = (int)((v.y - mn) * scale); b1 = b1 > NBINS - 1 ? NBINS - 1 : b1;
        int b2 = (int)((v.z - mn) * scale); b2 = b2 > NBINS - 1 ? NBINS - 1 : b2;
        int b3 = (int)((v.w - mn) * scale); b3 = b3 > NBINS - 1 ? NBINS - 1 : b3;
        atomicAdd(&h[base + b0], 1u);
        atomicAdd(&h[base + b1], 1u);
        atomicAdd(&h[base + b2], 1u);
        atomicAdd(&h[base + b3], 1u);
    }
    __syncthreads();
    unsigned int* gh = (unsigned int*)ws + 2;
    for (int i = threadIdx.x; i < NBINS; i += blockDim.x) {
        unsigned int s = 0;
        #pragma unroll
        for (int c = 0; c < NCOPY; ++c) s += h[c * HSTRIDE + i];
        if (s) atomicAdd(&gh[i], s);
    }
}

__global__ void hrt_finalize(const unsigned int* __restrict__ ws, float* __restrict__ out) {
    if (threadIdx.x != 0 || blockIdx.x != 0) return;
    const unsigned int* h = ws + 2;
    unsigned long long total = 0;
    for (int i = 0; i < NBINS; ++i) total += h[i];
    double thr_lo = (double)total * ((1.0 - 0.99) / 2.0);
    double thr_hi = (double)total * ((1.0 + 0.99) / 2.0);
    unsigned long long cum = 0;
    int lo = 0, hi = 0;
    bool flo = false, fhi = false;
    for (int i = 0; i < NBINS; ++i) {
        cum += h[i];
        double c = (double)cum;
        if (!flo && c > thr_lo) { lo = i; flo = true; }
        if (!fhi && c > thr_hi) { hi = i; fhi = true; }
    }
    float mn = o2f(ws[0]), mx = o2f(ws[1]);
    // np.linspace computes in f64 then casts to f32
    double delta = ((double)mx - (double)mn) / (double)NBINS;
    out[0] = (float)((double)mn + (double)lo * delta);
    out[1] = (float)((double)mn + (double)hi * delta);
}

extern "C" void kernel_launch(void* const* d_in, const int* in_sizes, int n_in,
                              void* d_out, int out_size, void* d_ws, size_t ws_size,
                              hipStream_t stream) {
    const float4* in = (const float4*)d_in[0];
    int n = in_sizes[0];
    int n4 = n / 4;
    unsigned int* ws = (unsigned int*)d_ws;
    float* out = (float*)d_out;

    hrt_init<<<1, NBINS, 0, stream>>>(ws);
    hrt_minmax<<<2048, 256, 0, stream>>>(in, n4, ws);
    hrt_hist<<<2048, 256, 0, stream>>>(in, n4, ws);
    hrt_finalize<<<1, 64, 0, stream>>>(ws, out);
}

// Round 3
// 117.936 us; speedup vs baseline: 1.6716x; 1.6716x over previous
//
#include <hip/hip_runtime.h>

#define NBINS 256
#define NCOPY 16
#define HSTRIDE 257   // 257 % 32 == 1 -> copy c of bin b sits in bank (c + b) % 32
#define NBLK 2048     // blocks for the two streaming passes
#define RBLK 64       // reduce-stage blocks; each handles NBLK/RBLK = 32 rows

// ws layout (as float*/uint*):
//   f[0], f[1]                  final min, max          (written by combine)
//   f[2+2b], f[3+2b], b<NBLK    per-block min/max       (written by minmax)
//   u[PT_OFF  + r*256 + bin]    partial hists, NBLK rows (written by hist)
//   u[PT2_OFF + j*256 + bin]    reduced partials, RBLK rows
#define PT_OFF  8192
#define PT2_OFF (PT_OFF + NBLK * NBINS)

__global__ void hrt_minmax(const float4* __restrict__ in, int n4, float* __restrict__ wsf) {
    float mn = INFINITY, mx = -INFINITY;
    int stride = gridDim.x * blockDim.x;
    for (int i = blockIdx.x * blockDim.x + threadIdx.x; i < n4; i += stride) {
        float4 v = in[i];
        mn = fminf(mn, fminf(fminf(v.x, v.y), fminf(v.z, v.w)));
        mx = fmaxf(mx, fmaxf(fmaxf(v.x, v.y), fmaxf(v.z, v.w)));
    }
    #pragma unroll
    for (int off = 32; off > 0; off >>= 1) {
        mn = fminf(mn, __shfl_down(mn, off));
        mx = fmaxf(mx, __shfl_down(mx, off));
    }
    __shared__ float smn[4], smx[4];
    int lane = threadIdx.x & 63, wid = threadIdx.x >> 6;
    if (lane == 0) { smn[wid] = mn; smx[wid] = mx; }
    __syncthreads();
    if (threadIdx.x == 0) {
        #pragma unroll
        for (int w = 1; w < 4; ++w) { mn = fminf(mn, smn[w]); mx = fmaxf(mx, smx[w]); }
        wsf[2 + 2 * blockIdx.x] = mn;   // non-atomic private slot
        wsf[3 + 2 * blockIdx.x] = mx;
    }
}

__global__ void hrt_combine(float* __restrict__ wsf) {
    float mn = INFINITY, mx = -INFINITY;
    for (int i = threadIdx.x; i < NBLK; i += 256) {
        mn = fminf(mn, wsf[2 + 2 * i]);
        mx = fmaxf(mx, wsf[3 + 2 * i]);
    }
    #pragma unroll
    for (int off = 32; off > 0; off >>= 1) {
        mn = fminf(mn, __shfl_down(mn, off));
        mx = fmaxf(mx, __shfl_down(mx, off));
    }
    __shared__ float smn[4], smx[4];
    int lane = threadIdx.x & 63, wid = threadIdx.x >> 6;
    if (lane == 0) { smn[wid] = mn; smx[wid] = mx; }
    __syncthreads();
    if (threadIdx.x == 0) {
        #pragma unroll
        for (int w = 1; w < 4; ++w) { mn = fminf(mn, smn[w]); mx = fmaxf(mx, smx[w]); }
        wsf[0] = mn;
        wsf[1] = mx;
    }
}

__global__ void hrt_hist(const float4* __restrict__ in, int n4,
                         const float* __restrict__ wsf, unsigned int* __restrict__ wsu) {
    __shared__ unsigned int h[NCOPY * HSTRIDE];
    for (int i = threadIdx.x; i < NCOPY * HSTRIDE; i += blockDim.x)
        h[i] = 0u;
    __syncthreads();
    float mn = wsf[0];
    float mx = wsf[1];
    float scale = (float)NBINS / (mx - mn);
    unsigned int base = (threadIdx.x & (NCOPY - 1)) * HSTRIDE;
    int stride = gridDim.x * blockDim.x;
    for (int i = blockIdx.x * blockDim.x + threadIdx.x; i < n4; i += stride) {
        float4 v = in[i];
        int b0 = (int)((v.x - mn) * scale); b0 = b0 > NBINS - 1 ? NBINS - 1 : b0;
        int b1 = (int)((v.y - mn) * scale); b1 = b1 > NBINS - 1 ? NBINS - 1 : b1;
        int b2 = (int)((v.z - mn) * scale); b2 = b2 > NBINS - 1 ? NBINS - 1 : b2;
        int b3 = (int)((v.w - mn) * scale); b3 = b3 > NBINS - 1 ? NBINS - 1 : b3;
        atomicAdd(&h[base + b0], 1u);
        atomicAdd(&h[base + b1], 1u);
        atomicAdd(&h[base + b2], 1u);
        atomicAdd(&h[base + b3], 1u);
    }
    __syncthreads();
    unsigned int* pt = wsu + PT_OFF;
    for (int i = threadIdx.x; i < NBINS; i += blockDim.x) {
        unsigned int s = 0;
        #pragma unroll
        for (int c = 0; c < NCOPY; ++c) s += h[c * HSTRIDE + i];
        pt[blockIdx.x * NBINS + i] = s;   // non-atomic coalesced dump
    }
}

__global__ void hrt_reduce(unsigned int* __restrict__ wsu) {
    const unsigned int* pt = wsu + PT_OFF;
    unsigned int* pt2 = wsu + PT2_OFF;
    int t = threadIdx.x;
    int r0 = blockIdx.x * (NBLK / RBLK);
    unsigned int s = 0;
    for (int r = 0; r < NBLK / RBLK; ++r)
        s += pt[(r0 + r) * NBINS + t];    // coalesced across threads
    pt2[blockIdx.x * NBINS + t] = s;
}

__global__ void hrt_finalize(const float* __restrict__ wsf,
                             const unsigned int* __restrict__ wsu,
                             float* __restrict__ out) {
    const unsigned int* pt2 = wsu + PT2_OFF;
    int t = threadIdx.x;
    unsigned long long s = 0;
    for (int j = 0; j < RBLK; ++j)
        s += pt2[j * NBINS + t];          // coalesced
    __shared__ unsigned long long cum[NBINS];
    cum[t] = s;
    __syncthreads();
    // Hillis-Steele inclusive scan over 256 bins
    for (int off = 1; off < NBINS; off <<= 1) {
        unsigned long long v = cum[t];
        if (t >= off) v += cum[t - off];
        __syncthreads();
        cum[t] = v;
        __syncthreads();
    }
    unsigned long long total = cum[NBINS - 1];
    double thr_lo = (double)total * ((1.0 - 0.99) / 2.0);
    double thr_hi = (double)total * ((1.0 + 0.99) / 2.0);
    double c  = (double)cum[t];
    double cp = (t == 0) ? -1.0 : (double)cum[t - 1];  // cum before this bin
    float mn = wsf[0], mx = wsf[1];
    double delta = ((double)mx - (double)mn) / (double)NBINS;
    bool cross_lo = (c > thr_lo) && (t == 0 || cp <= thr_lo);
    bool cross_hi = (c > thr_hi) && (t == 0 || cp <= thr_hi);
    if (cross_lo) out[0] = (float)((double)mn + (double)t * delta);
    if (cross_hi) out[1] = (float)((double)mn + (double)t * delta);
}

extern "C" void kernel_launch(void* const* d_in, const int* in_sizes, int n_in,
                              void* d_out, int out_size, void* d_ws, size_t ws_size,
                              hipStream_t stream) {
    const float4* in = (const float4*)d_in[0];
    int n = in_sizes[0];
    int n4 = n / 4;
    float* wsf = (float*)d_ws;
    unsigned int* wsu = (unsigned int*)d_ws;
    float* out = (float*)d_out;

    hrt_minmax<<<NBLK, 256, 0, stream>>>(in, n4, wsf);
    hrt_combine<<<1, 256, 0, stream>>>(wsf);
    hrt_hist<<<NBLK, 256, 0, stream>>>(in, n4, wsf, wsu);
    hrt_reduce<<<RBLK, 256, 0, stream>>>(wsu);
    hrt_finalize<<<1, 256, 0, stream>>>(wsf, wsu, out);
}

// Round 4
// 96.842 us; speedup vs baseline: 2.0356x; 1.2178x over previous
//
#include <hip/hip_runtime.h>

#define NBINS 256
#define NBUCK 8192            // 2^13 bit-space buckets (sign+exp+4 mantissa bits)
#define BSHIFT 19             // f2o(x) >> 19 -> bucket index
#define P1BLK 1280            // pass1 blocks: 5/CU (32 KB LDS each)
#define RG 64                 // reduceA row groups (1280/64 = 20 rows each)
#define CG 8                  // reduceA col groups (8192/8 = 1024 cols each)

// ws layout (uint32 words):
//   [0 .. 2*P1BLK)          per-block ordered min/max pairs (u[2b], u[2b+1])
//   [HOFF ..)               P1BLK x NBUCK partial histograms
//   [MOFF ..)               RG x NBUCK reduced partials
//   [FOFF ..)               final NBUCK histogram
#define HOFF 4096u
#define MOFF (HOFF + (unsigned)P1BLK * NBUCK)   // 10,489,856
#define FOFF (MOFF + (unsigned)RG * NBUCK)      // 11,014,144

__device__ __forceinline__ unsigned int f2o(float f) {
    unsigned int u = __float_as_uint(f);
    return (u & 0x80000000u) ? ~u : (u | 0x80000000u);
}
__device__ __forceinline__ float o2f(unsigned int u) {
    unsigned int v = (u & 0x80000000u) ? (u & 0x7fffffffu) : ~u;
    return __uint_as_float(v);
}
__device__ __forceinline__ unsigned int umn(unsigned int a, unsigned int b) { return a < b ? a : b; }
__device__ __forceinline__ unsigned int umx(unsigned int a, unsigned int b) { return a > b ? a : b; }

__global__ void __launch_bounds__(256) hrt_pass1(const float4* __restrict__ in, int n4,
                                                 unsigned int* __restrict__ wsu) {
    __shared__ unsigned int h[NBUCK];
    for (int i = threadIdx.x; i < NBUCK; i += 256) h[i] = 0u;
    __syncthreads();
    unsigned int mnu = 0xFFFFFFFFu, mxu = 0u;
    int stride = gridDim.x * 256;
    for (int i = blockIdx.x * 256 + threadIdx.x; i < n4; i += stride) {
        float4 v = in[i];
        unsigned int u0 = f2o(v.x), u1 = f2o(v.y), u2 = f2o(v.z), u3 = f2o(v.w);
        mnu = umn(mnu, umn(umn(u0, u1), umn(u2, u3)));
        mxu = umx(mxu, umx(umx(u0, u1), umx(u2, u3)));
        atomicAdd(&h[u0 >> BSHIFT], 1u);
        atomicAdd(&h[u1 >> BSHIFT], 1u);
        atomicAdd(&h[u2 >> BSHIFT], 1u);
        atomicAdd(&h[u3 >> BSHIFT], 1u);
    }
    // block-reduce min/max
    #pragma unroll
    for (int off = 32; off > 0; off >>= 1) {
        mnu = umn(mnu, (unsigned int)__shfl_down((int)mnu, off));
        mxu = umx(mxu, (unsigned int)__shfl_down((int)mxu, off));
    }
    __shared__ unsigned int smn[4], smx[4];
    int lane = threadIdx.x & 63, wid = threadIdx.x >> 6;
    if (lane == 0) { smn[wid] = mnu; smx[wid] = mxu; }
    __syncthreads();
    if (threadIdx.x == 0) {
        #pragma unroll
        for (int w = 1; w < 4; ++w) { mnu = umn(mnu, smn[w]); mxu = umx(mxu, smx[w]); }
        wsu[2 * blockIdx.x]     = mnu;
        wsu[2 * blockIdx.x + 1] = mxu;
    }
    __syncthreads();
    // non-atomic coalesced dump of this block's histogram row
    unsigned int* row = wsu + HOFF + (unsigned)blockIdx.x * NBUCK;
    for (int k = threadIdx.x; k < NBUCK; k += 256) row[k] = h[k];
}

__global__ void __launch_bounds__(256) hrt_reduceA(unsigned int* __restrict__ wsu) {
    int rg = blockIdx.x >> 3, cg = blockIdx.x & 7, t = threadIdx.x;
    const uint4* src = (const uint4*)(wsu + HOFF);   // row stride = 2048 uint4
    uint4 s = make_uint4(0u, 0u, 0u, 0u);
    int base = cg * 256 + t;
    int r0 = rg * (P1BLK / RG);
    for (int r = r0; r < r0 + P1BLK / RG; ++r) {
        uint4 v = src[r * (NBUCK / 4) + base];
        s.x += v.x; s.y += v.y; s.z += v.z; s.w += v.w;
    }
    ((uint4*)(wsu + MOFF))[rg * (NBUCK / 4) + base] = s;
}

__global__ void __launch_bounds__(256) hrt_reduceB(unsigned int* __restrict__ wsu) {
    int b = blockIdx.x, t = threadIdx.x;
    const uint4* src = (const uint4*)(wsu + MOFF);
    uint4 s = make_uint4(0u, 0u, 0u, 0u);
    int base = b * 256 + t;
    for (int r = 0; r < RG; ++r) {
        uint4 v = src[r * (NBUCK / 4) + base];
        s.x += v.x; s.y += v.y; s.z += v.z; s.w += v.w;
    }
    ((uint4*)(wsu + FOFF))[base] = s;
}

__global__ void __launch_bounds__(1024) hrt_finalize(const unsigned int* __restrict__ wsu,
                                                     float* __restrict__ out) {
    __shared__ unsigned int excl[NBUCK + 1];
    __shared__ unsigned int ssum[1024];
    __shared__ unsigned int redmn[16], redmx[16];
    __shared__ float sm[2];
    int t = threadIdx.x;

    // combine per-block min/max (exact, integer order-space)
    unsigned int mnu = 0xFFFFFFFFu, mxu = 0u;
    for (int i = t; i < P1BLK; i += 1024) {
        mnu = umn(mnu, wsu[2 * i]);
        mxu = umx(mxu, wsu[2 * i + 1]);
    }
    #pragma unroll
    for (int off = 32; off > 0; off >>= 1) {
        mnu = umn(mnu, (unsigned int)__shfl_down((int)mnu, off));
        mxu = umx(mxu, (unsigned int)__shfl_down((int)mxu, off));
    }
    int lane = t & 63, wid = t >> 6;
    if (lane == 0) { redmn[wid] = mnu; redmx[wid] = mxu; }

    // load 8 buckets per thread, local sum
    const uint4* fh = (const uint4*)(wsu + FOFF);
    uint4 a = fh[2 * t], b = fh[2 * t + 1];
    unsigned int c[8] = { a.x, a.y, a.z, a.w, b.x, b.y, b.z, b.w };
    unsigned int s8 = 0;
    #pragma unroll
    for (int j = 0; j < 8; ++j) s8 += c[j];
    ssum[t] = s8;
    __syncthreads();

    // Hillis-Steele inclusive scan over 1024 thread-sums
    for (int off = 1; off < 1024; off <<= 1) {
        unsigned int v = ssum[t];
        if (t >= off) v += ssum[t - off];
        __syncthreads();
        ssum[t] = v;
        __syncthreads();
    }
    unsigned int run = ssum[t] - s8;   // exclusive base for this thread's 8 buckets
    #pragma unroll
    for (int j = 0; j < 8; ++j) { excl[8 * t + j] = run; run += c[j]; }
    if (t == 1023) excl[NBUCK] = run;  // total count

    if (t == 0) {
        unsigned int m1 = 0xFFFFFFFFu, m2 = 0u;
        #pragma unroll
        for (int w = 0; w < 16; ++w) { m1 = umn(m1, redmn[w]); m2 = umx(m2, redmx[w]); }
        sm[0] = o2f(m1); sm[1] = o2f(m2);
    }
    __syncthreads();

    if (t < NBINS) {
        double mn = (double)sm[0], mx = (double)sm[1];
        unsigned int total = excl[NBUCK];
        double delta = (mx - mn) / (double)NBINS;
        double thr0 = (double)total * ((1.0 - 0.99) / 2.0);
        double thr1 = (double)total * ((1.0 + 0.99) / 2.0);

        // est. cumulative count of {x < e}: exact bucket prefix + in-bucket linear interp
        auto estcum = [&](double e) -> double {
            unsigned int u = f2o((float)e);
            unsigned int k = u >> BSHIFT;
            unsigned int lou = k << BSHIFT;
            unsigned int hiu = (k == NBUCK - 1) ? 0xFFFFFFFFu : ((k + 1) << BSHIFT);
            double flo = (double)o2f(lou), fhi = (double)o2f(hiu);
            double fr = (e - flo) / (fhi - flo);
            fr = fr < 0.0 ? 0.0 : (fr > 1.0 ? 1.0 : fr);
            double cl = (double)excl[k], ch = (double)excl[k + 1];
            return cl + (ch - cl) * fr;
        };

        double c_hi = estcum(mn + (double)(t + 1) * delta);  // cum[t]   (ref indexing)
        double c_lo = estcum(mn + (double)t * delta);        // cum[t-1]
        // first-crossing: cum[t] > thr and cum[t-1] <= thr  (monotone -> unique writer)
        if (c_hi > thr0 && !(c_lo > thr0)) out[0] = (float)(mn + (double)t * delta);
        if (c_hi > thr1 && !(c_lo > thr1)) out[1] = (float)(mn + (double)t * delta);
    }
}

extern "C" void kernel_launch(void* const* d_in, const int* in_sizes, int n_in,
                              void* d_out, int out_size, void* d_ws, size_t ws_size,
                              hipStream_t stream) {
    const float4* in = (const float4*)d_in[0];
    int n = in_sizes[0];
    int n4 = n / 4;
    unsigned int* wsu = (unsigned int*)d_ws;
    float* out = (float*)d_out;

    hrt_pass1<<<P1BLK, 256, 0, stream>>>(in, n4, wsu);
    hrt_reduceA<<<RG * CG, 256, 0, stream>>>(wsu);
    hrt_reduceB<<<8, 256, 0, stream>>>(wsu);
    hrt_finalize<<<1, 1024, 0, stream>>>(wsu, out);
}

// Round 5
// 72.443 us; speedup vs baseline: 2.7213x; 1.3368x over previous
//
#include <hip/hip_runtime.h>

#define NBINS 256
#define NBUCK 8192            // 2^13 bit-space buckets (sign+exp+4 mantissa bits)
#define BSHIFT 19             // f2o(x) >> 19 -> bucket index
#define P1BLK 1280            // pass1 blocks: 5/CU (32 KB LDS each)
#define RG 64                 // reduceA row groups (1280/64 = 20 rows each)
#define CG2 4                 // reduceA col groups (2048 buckets each)

// ws layout (uint32 word offsets):
//   [0 .. 2*P1BLK)   per-block ordered min/max pairs (u[2b], u[2b+1])
//   HOFF_W           P1BLK x NBUCK partial hists, PACKED USHORT (NBUCK/2 words/row)
//   MOFF_W           RG x NBUCK reduced partials (u32)
//   FOFF_W           final NBUCK histogram (u32)
#define HOFF_W 4096u
#define MOFF_W (HOFF_W + (unsigned)P1BLK * (NBUCK / 2))   // 5,246,976
#define FOFF_W (MOFF_W + (unsigned)RG * NBUCK)            // 5,771,264

__device__ __forceinline__ unsigned int f2o(float f) {
    unsigned int u = __float_as_uint(f);
    return u ^ ((unsigned int)(((int)u) >> 31) | 0x80000000u);
}
__device__ __forceinline__ float o2f(unsigned int u) {
    unsigned int v = (u & 0x80000000u) ? (u & 0x7fffffffu) : ~u;
    return __uint_as_float(v);
}
__device__ __forceinline__ unsigned int umn(unsigned int a, unsigned int b) { return a < b ? a : b; }
__device__ __forceinline__ unsigned int umx(unsigned int a, unsigned int b) { return a > b ? a : b; }

// n8 = n/8; each thread consumes two contiguous float4 (32 B) per iteration.
__global__ void __launch_bounds__(256) hrt_pass1(const float4* __restrict__ in, int n8,
                                                 unsigned int* __restrict__ wsu) {
    __shared__ unsigned int h[NBUCK];
    for (int i = threadIdx.x; i < NBUCK; i += 256) h[i] = 0u;
    __syncthreads();
    unsigned int mnu = 0xFFFFFFFFu, mxu = 0u;
    int stride = P1BLK * 256;
    for (int i = blockIdx.x * 256 + threadIdx.x; i < n8; i += stride) {
        float4 v0 = in[2 * i];
        float4 v1 = in[2 * i + 1];
        unsigned int u0 = f2o(v0.x), u1 = f2o(v0.y), u2 = f2o(v0.z), u3 = f2o(v0.w);
        unsigned int u4 = f2o(v1.x), u5 = f2o(v1.y), u6 = f2o(v1.z), u7 = f2o(v1.w);
        unsigned int a = umn(umn(u0, u1), umn(u2, u3));
        unsigned int b = umn(umn(u4, u5), umn(u6, u7));
        mnu = umn(mnu, umn(a, b));
        a = umx(umx(u0, u1), umx(u2, u3));
        b = umx(umx(u4, u5), umx(u6, u7));
        mxu = umx(mxu, umx(a, b));
        atomicAdd(&h[u0 >> BSHIFT], 1u);
        atomicAdd(&h[u1 >> BSHIFT], 1u);
        atomicAdd(&h[u2 >> BSHIFT], 1u);
        atomicAdd(&h[u3 >> BSHIFT], 1u);
        atomicAdd(&h[u4 >> BSHIFT], 1u);
        atomicAdd(&h[u5 >> BSHIFT], 1u);
        atomicAdd(&h[u6 >> BSHIFT], 1u);
        atomicAdd(&h[u7 >> BSHIFT], 1u);
    }
    #pragma unroll
    for (int off = 32; off > 0; off >>= 1) {
        mnu = umn(mnu, (unsigned int)__shfl_down((int)mnu, off));
        mxu = umx(mxu, (unsigned int)__shfl_down((int)mxu, off));
    }
    __shared__ unsigned int smn[4], smx[4];
    int lane = threadIdx.x & 63, wid = threadIdx.x >> 6;
    if (lane == 0) { smn[wid] = mnu; smx[wid] = mxu; }
    __syncthreads();
    if (threadIdx.x == 0) {
        #pragma unroll
        for (int w = 1; w < 4; ++w) { mnu = umn(mnu, smn[w]); mxu = umx(mxu, smx[w]); }
        wsu[2 * blockIdx.x]     = mnu;
        wsu[2 * blockIdx.x + 1] = mxu;
    }
    __syncthreads();
    // packed-ushort dump: per-block per-bucket count <= 51200 < 65536 structurally
    unsigned int* row = wsu + HOFF_W + (unsigned)blockIdx.x * (NBUCK / 2);
    for (int k = threadIdx.x; k < NBUCK / 2; k += 256)
        row[k] = (h[2 * k] & 0xFFFFu) | (h[2 * k + 1] << 16);
}

// 256 blocks: 64 row-groups (20 rows) x 4 col-groups (2048 buckets); 8 buckets/thread
__global__ void __launch_bounds__(256) hrt_reduceA(unsigned int* __restrict__ wsu) {
    int rg = blockIdx.x >> 2, cg = blockIdx.x & 3, t = threadIdx.x;
    const uint4* src = (const uint4*)(wsu + HOFF_W);  // row = NBUCK/8 = 1024 uint4
    unsigned int s[8] = {0, 0, 0, 0, 0, 0, 0, 0};
    int base = cg * 256 + t;                          // uint4 index within row
    int r0 = rg * (P1BLK / RG);
    for (int r = r0; r < r0 + P1BLK / RG; ++r) {
        uint4 v = src[r * (NBUCK / 8) + base];
        s[0] += v.x & 0xFFFFu; s[1] += v.x >> 16;
        s[2] += v.y & 0xFFFFu; s[3] += v.y >> 16;
        s[4] += v.z & 0xFFFFu; s[5] += v.z >> 16;
        s[6] += v.w & 0xFFFFu; s[7] += v.w >> 16;
    }
    uint4* dst = (uint4*)(wsu + MOFF_W);              // row = NBUCK/4 = 2048 uint4
    dst[rg * (NBUCK / 4) + base * 2]     = make_uint4(s[0], s[1], s[2], s[3]);
    dst[rg * (NBUCK / 4) + base * 2 + 1] = make_uint4(s[4], s[5], s[6], s[7]);
}

__global__ void __launch_bounds__(256) hrt_reduceB(unsigned int* __restrict__ wsu) {
    int b = blockIdx.x, t = threadIdx.x;
    const uint4* src = (const uint4*)(wsu + MOFF_W);
    uint4 s = make_uint4(0u, 0u, 0u, 0u);
    int base = b * 256 + t;
    for (int r = 0; r < RG; ++r) {
        uint4 v = src[r * (NBUCK / 4) + base];
        s.x += v.x; s.y += v.y; s.z += v.z; s.w += v.w;
    }
    ((uint4*)(wsu + FOFF_W))[base] = s;
}

__global__ void __launch_bounds__(1024) hrt_finalize(const unsigned int* __restrict__ wsu,
                                                     float* __restrict__ out) {
    __shared__ unsigned int excl[NBUCK + 1];
    __shared__ unsigned int ssum[1024];
    __shared__ unsigned int redmn[16], redmx[16];
    __shared__ float sm[2];
    int t = threadIdx.x;

    unsigned int mnu = 0xFFFFFFFFu, mxu = 0u;
    for (int i = t; i < P1BLK; i += 1024) {
        mnu = umn(mnu, wsu[2 * i]);
        mxu = umx(mxu, wsu[2 * i + 1]);
    }
    #pragma unroll
    for (int off = 32; off > 0; off >>= 1) {
        mnu = umn(mnu, (unsigned int)__shfl_down((int)mnu, off));
        mxu = umx(mxu, (unsigned int)__shfl_down((int)mxu, off));
    }
    int lane = t & 63, wid = t >> 6;
    if (lane == 0) { redmn[wid] = mnu; redmx[wid] = mxu; }

    const uint4* fh = (const uint4*)(wsu + FOFF_W);
    uint4 a = fh[2 * t], b = fh[2 * t + 1];
    unsigned int c[8] = { a.x, a.y, a.z, a.w, b.x, b.y, b.z, b.w };
    unsigned int s8 = 0;
    #pragma unroll
    for (int j = 0; j < 8; ++j) s8 += c[j];
    ssum[t] = s8;
    __syncthreads();

    for (int off = 1; off < 1024; off <<= 1) {
        unsigned int v = ssum[t];
        if (t >= off) v += ssum[t - off];
        __syncthreads();
        ssum[t] = v;
        __syncthreads();
    }
    unsigned int run = ssum[t] - s8;
    #pragma unroll
    for (int j = 0; j < 8; ++j) { excl[8 * t + j] = run; run += c[j]; }
    if (t == 1023) excl[NBUCK] = run;

    if (t == 0) {
        unsigned int m1 = 0xFFFFFFFFu, m2 = 0u;
        #pragma unroll
        for (int w = 0; w < 16; ++w) { m1 = umn(m1, redmn[w]); m2 = umx(m2, redmx[w]); }
        sm[0] = o2f(m1); sm[1] = o2f(m2);
    }
    __syncthreads();

    if (t < NBINS) {
        double mn = (double)sm[0], mx = (double)sm[1];
        unsigned int total = excl[NBUCK];
        double delta = (mx - mn) / (double)NBINS;
        double thr0 = (double)total * ((1.0 - 0.99) / 2.0);
        double thr1 = (double)total * ((1.0 + 0.99) / 2.0);

        auto estcum = [&](double e) -> double {
            unsigned int u = f2o((float)e);
            unsigned int k = u >> BSHIFT;
            unsigned int lou = k << BSHIFT;
            unsigned int hiu = (k == NBUCK - 1) ? 0xFFFFFFFFu : ((k + 1) << BSHIFT);
            double flo = (double)o2f(lou), fhi = (double)o2f(hiu);
            double fr = (e - flo) / (fhi - flo);
            fr = fr < 0.0 ? 0.0 : (fr > 1.0 ? 1.0 : fr);
            double cl = (double)excl[k], ch = (double)excl[k + 1];
            return cl + (ch - cl) * fr;
        };

        double c_hi = estcum(mn + (double)(t + 1) * delta);
        double c_lo = estcum(mn + (double)t * delta);
        if (c_hi > thr0 && !(c_lo > thr0)) out[0] = (float)(mn + (double)t * delta);
        if (c_hi > thr1 && !(c_lo > thr1)) out[1] = (float)(mn + (double)t * delta);
    }
}

extern "C" void kernel_launch(void* const* d_in, const int* in_sizes, int n_in,
                              void* d_out, int out_size, void* d_ws, size_t ws_size,
                              hipStream_t stream) {
    const float4* in = (const float4*)d_in[0];
    int n = in_sizes[0];
    int n8 = n / 8;
    unsigned int* wsu = (unsigned int*)d_ws;
    float* out = (float*)d_out;

    hrt_pass1<<<P1BLK, 256, 0, stream>>>(in, n8, wsu);
    hrt_reduceA<<<RG * CG2, 256, 0, stream>>>(wsu);
    hrt_reduceB<<<8, 256, 0, stream>>>(wsu);
    hrt_finalize<<<1, 1024, 0, stream>>>(wsu, out);
}